// Round 7
// baseline (4770.314 us; speedup 1.0000x reference)
//
#include <hip/hip_runtime.h>
#include <math.h>

typedef float f4 __attribute__((ext_vector_type(4)));

// Problem constants
constexpr int TT = 512;   // sequence length
constexpr int BB = 64;    // batch
constexpr int EE = 256;   // embed dim
constexpr int HH = 256;   // hidden
constexpr int SS = 64;    // states
constexpr int BH = BB * HH;       // 16384
constexpr int KB16 = HH * BB;     // floats per t-slice (16384)

// ---------------------------------------------------------------------------
// embT[t][k][b] = embed[obs[t][b]][k]  (transposed embedding sequence)
// ---------------------------------------------------------------------------
__global__ __launch_bounds__(256) void embT_prep(
    const int* __restrict__ obs, const float* __restrict__ embed,
    float* __restrict__ embT)
{
    const int t   = blockIdx.x;
    const int tid = threadIdx.x;
    const int b   = tid & 63;
    const int kc  = tid >> 6;                       // 0..3
    const int tok = obs[t * BB + b];
    const float4* er = (const float4*)(embed + (size_t)tok * EE);
    float* dst = embT + (size_t)t * KB16;
    #pragma unroll
    for (int i = 0; i < 16; ++i) {
        const int k4 = kc * 16 + i;
        float4 v = er[k4];
        const int k = k4 * 4;
        dst[(k + 0) * 64 + b] = v.x;
        dst[(k + 1) * 64 + b] = v.y;
        dst[(k + 2) * 64 + b] = v.z;
        dst[(k + 3) * 64 + b] = v.w;
    }
}

// ---------------------------------------------------------------------------
// Persistent BiLSTM recurrence, dataflow-synchronized (poll-on-data).
// Grid 256 = 2 dirs x 128 ublocks; 512 threads (8 waves); 1 block/CU, all
// blocks co-resident -> deadlock-free (plus a bounded poll as a hard
// guarantee the kernel always terminates).
// h history layout: hsT[t][b][u] (u contiguous) so each thread's 32 h-values
// are 128B contiguous -> poll = ONE asm statement with 8 dwordx4 sc0/sc1
// loads off one base pointer + a single vmcnt(0): one L3 round trip per
// poll iteration. Sentinel = 0xFFFFFFFF bytes (memset 0xFF), unreachable
// for h=o*tanh(c) from finite inputs.
// FMA order per accumulator: x k-ascending then h k-ascending (= R3/R4,
// bit-exact).
// ---------------------------------------------------------------------------
__global__ __launch_bounds__(512, 2) void lstm_persist(
    const float* __restrict__ embT,
    const float* __restrict__ Wih_f, const float* __restrict__ Whh_f,
    const float* __restrict__ bih_f, const float* __restrict__ bhh_f,
    const float* __restrict__ Wih_b, const float* __restrict__ Whh_b,
    const float* __restrict__ bih_b, const float* __restrict__ bhh_b,
    const float* __restrict__ h0, const float* __restrict__ c0,
    float* __restrict__ hsTf, float* __restrict__ hsTb)
{
    __shared__ float buf[8192];    // 32 KB: double-buffered partial exchange
    const int tid  = threadIdx.x;
    const int b    = tid & 63;
    const int w    = tid >> 6;     // 0..7 K-chunk index
    const int bx   = blockIdx.x;
    const int dir  = bx & 1;
    const int ublk = bx >> 1;      // 0..127
    const int u0   = ublk * 2;

    const float* Wih = dir ? Wih_b : Wih_f;
    const float* Whh = dir ? Whh_b : Whh_f;
    const float* bih = dir ? bih_b : bih_f;
    const float* bhh = dir ? bhh_b : bhh_f;
    float* hsT = dir ? hsTb : hsTf;

    const int kbase = w * 32;
    const int kb_s  = __builtin_amdgcn_readfirstlane(kbase);

    // 8 gate-row weight bases (wave-uniform -> scalar K$ loads)
    const float* Wx0 = Wih + (size_t)(0 * 256 + u0    ) * EE + kb_s;
    const float* Wx1 = Wih + (size_t)(0 * 256 + u0 + 1) * EE + kb_s;
    const float* Wx2 = Wih + (size_t)(1 * 256 + u0    ) * EE + kb_s;
    const float* Wx3 = Wih + (size_t)(1 * 256 + u0 + 1) * EE + kb_s;
    const float* Wx4 = Wih + (size_t)(2 * 256 + u0    ) * EE + kb_s;
    const float* Wx5 = Wih + (size_t)(2 * 256 + u0 + 1) * EE + kb_s;
    const float* Wx6 = Wih + (size_t)(3 * 256 + u0    ) * EE + kb_s;
    const float* Wx7 = Wih + (size_t)(3 * 256 + u0 + 1) * EE + kb_s;
    const float* Wh0 = Whh + (size_t)(0 * 256 + u0    ) * HH + kb_s;
    const float* Wh1 = Whh + (size_t)(0 * 256 + u0 + 1) * HH + kb_s;
    const float* Wh2 = Whh + (size_t)(1 * 256 + u0    ) * HH + kb_s;
    const float* Wh3 = Whh + (size_t)(1 * 256 + u0 + 1) * HH + kb_s;
    const float* Wh4 = Whh + (size_t)(2 * 256 + u0    ) * HH + kb_s;
    const float* Wh5 = Whh + (size_t)(2 * 256 + u0 + 1) * HH + kb_s;
    const float* Wh6 = Whh + (size_t)(3 * 256 + u0    ) * HH + kb_s;
    const float* Wh7 = Whh + (size_t)(3 * 256 + u0 + 1) * HH + kb_s;

    // persistent cell state + biases (tid<128: uo = tid>>6, unit u0+uo)
    float c_reg = 0.0f;
    float bias0 = 0.f, bias1 = 0.f, bias2 = 0.f, bias3 = 0.f;
    if (tid < 128) {
        const int uo = tid >> 6;
        const int u  = u0 + uo;
        c_reg = c0[dir * BH + b * HH + u];
        bias0 = bih[0 * 256 + u] + bhh[0 * 256 + u];
        bias1 = bih[1 * 256 + u] + bhh[1 * 256 + u];
        bias2 = bih[2 * 256 + u] + bhh[2 * 256 + u];
        bias3 = bih[3 * 256 + u] + bhh[3 * 256 + u];
    }

    for (int step = 0; step < TT; ++step) {
        const int t_emb = dir ? (TT - 1 - step) : step;

        float acc0 = 0.f, acc1 = 0.f, acc2 = 0.f, acc3 = 0.f;
        float acc4 = 0.f, acc5 = 0.f, acc6 = 0.f, acc7 = 0.f;

        // ---- x dots first (no h dependency; covers producer lag) ----
        {
            const float* xs = embT + (size_t)t_emb * KB16 + kbase * 64 + b;
            #pragma unroll 8
            for (int k = 0; k < 32; ++k) {
                const float x = xs[k * 64];
                acc0 = fmaf(x, Wx0[k], acc0);
                acc1 = fmaf(x, Wx1[k], acc1);
                acc2 = fmaf(x, Wx2[k], acc2);
                acc3 = fmaf(x, Wx3[k], acc3);
                acc4 = fmaf(x, Wx4[k], acc4);
                acc5 = fmaf(x, Wx5[k], acc5);
                acc6 = fmaf(x, Wx6[k], acc6);
                acc7 = fmaf(x, Wx7[k], acc7);
            }
        }

        // ---- h values: contiguous 128B per thread, poll-on-data ----
        f4 hq0, hq1, hq2, hq3, hq4, hq5, hq6, hq7;
        if (step == 0) {
            const f4* hp4 = (const f4*)(h0 + dir * BH + b * HH + kbase);
            hq0 = hp4[0]; hq1 = hp4[1]; hq2 = hp4[2]; hq3 = hp4[3];
            hq4 = hp4[4]; hq5 = hp4[5]; hq6 = hp4[6]; hq7 = hp4[7];
        } else {
            const int t_prev = dir ? (t_emb + 1) : (t_emb - 1);
            const float* hsrc = hsT + (size_t)t_prev * KB16 + b * HH + kbase;
            int spins = 0;
            for (;;) {
                asm volatile(
                    "global_load_dwordx4 %0, %8, off sc0 sc1\n\t"
                    "global_load_dwordx4 %1, %8, off offset:16 sc0 sc1\n\t"
                    "global_load_dwordx4 %2, %8, off offset:32 sc0 sc1\n\t"
                    "global_load_dwordx4 %3, %8, off offset:48 sc0 sc1\n\t"
                    "global_load_dwordx4 %4, %8, off offset:64 sc0 sc1\n\t"
                    "global_load_dwordx4 %5, %8, off offset:80 sc0 sc1\n\t"
                    "global_load_dwordx4 %6, %8, off offset:96 sc0 sc1\n\t"
                    "global_load_dwordx4 %7, %8, off offset:112 sc0 sc1\n\t"
                    "s_waitcnt vmcnt(0)"
                    : "=v"(hq0), "=v"(hq1), "=v"(hq2), "=v"(hq3),
                      "=v"(hq4), "=v"(hq5), "=v"(hq6), "=v"(hq7)
                    : "v"(hsrc)
                    : "memory");
                unsigned bad = 0;
                #pragma unroll
                for (int j = 0; j < 4; ++j) {
                    bad |= (__float_as_uint(hq0[j]) == 0xFFFFFFFFu);
                    bad |= (__float_as_uint(hq1[j]) == 0xFFFFFFFFu);
                    bad |= (__float_as_uint(hq2[j]) == 0xFFFFFFFFu);
                    bad |= (__float_as_uint(hq3[j]) == 0xFFFFFFFFu);
                    bad |= (__float_as_uint(hq4[j]) == 0xFFFFFFFFu);
                    bad |= (__float_as_uint(hq5[j]) == 0xFFFFFFFFu);
                    bad |= (__float_as_uint(hq6[j]) == 0xFFFFFFFFu);
                    bad |= (__float_as_uint(hq7[j]) == 0xFFFFFFFFu);
                }
                if (!__any(bad)) break;
                if (++spins > 16384) break;   // hard termination guarantee
                __builtin_amdgcn_s_sleep(1);
            }
        }

        // ---- h dots (k ascending: hq{i}[j] is k = i*4+j) ----
        {
            const f4* w0 = (const f4*)Wh0; const f4* w1 = (const f4*)Wh1;
            const f4* w2 = (const f4*)Wh2; const f4* w3 = (const f4*)Wh3;
            const f4* w4 = (const f4*)Wh4; const f4* w5 = (const f4*)Wh5;
            const f4* w6 = (const f4*)Wh6; const f4* w7 = (const f4*)Wh7;
            f4 hh[8] = {hq0, hq1, hq2, hq3, hq4, hq5, hq6, hq7};
            #pragma unroll
            for (int i = 0; i < 8; ++i) {
                const f4 h = hh[i];
                const f4 a = w0[i], bq = w1[i], c = w2[i], d = w3[i];
                const f4 e = w4[i], f = w5[i], g = w6[i], hw = w7[i];
                #pragma unroll
                for (int j = 0; j < 4; ++j) {
                    acc0 = fmaf(h[j], a[j],  acc0);
                    acc1 = fmaf(h[j], bq[j], acc1);
                    acc2 = fmaf(h[j], c[j],  acc2);
                    acc3 = fmaf(h[j], d[j],  acc3);
                    acc4 = fmaf(h[j], e[j],  acc4);
                    acc5 = fmaf(h[j], f[j],  acc5);
                    acc6 = fmaf(h[j], g[j],  acc6);
                    acc7 = fmaf(h[j], hw[j], acc7);
                }
            }
        }

        // ---- exchange partials: pb[w][dot], dot = r*64 + b (double-buffered) ----
        float* pb = buf + ((step & 1) << 12);
        pb[w * 512 + 0 * 64 + b] = acc0;
        pb[w * 512 + 1 * 64 + b] = acc1;
        pb[w * 512 + 2 * 64 + b] = acc2;
        pb[w * 512 + 3 * 64 + b] = acc3;
        pb[w * 512 + 4 * 64 + b] = acc4;
        pb[w * 512 + 5 * 64 + b] = acc5;
        pb[w * 512 + 6 * 64 + b] = acc6;
        pb[w * 512 + 7 * 64 + b] = acc7;
        __syncthreads();   // the ONLY per-step block sync

        // ---- cell update (128 threads: b, uo); fire-and-forget h store ----
        if (tid < 128) {
            const int uo = tid >> 6;
            const int u  = u0 + uo;
            float p0 = bias0, p1 = bias1, p2 = bias2, p3 = bias3;
            #pragma unroll
            for (int ww = 0; ww < 8; ++ww) {
                p0 += pb[ww * 512 + (0 * 2 + uo) * 64 + b];
                p1 += pb[ww * 512 + (1 * 2 + uo) * 64 + b];
                p2 += pb[ww * 512 + (2 * 2 + uo) * 64 + b];
                p3 += pb[ww * 512 + (3 * 2 + uo) * 64 + b];
            }
            const float ig = 1.0f / (1.0f + expf(-p0));
            const float fg = 1.0f / (1.0f + expf(-p1));
            const float gg = tanhf(p2);
            const float og = 1.0f / (1.0f + expf(-p3));
            c_reg = fg * c_reg + ig * gg;
            const float h = og * tanhf(c_reg);
            unsigned* dst = (unsigned*)(hsT + (size_t)t_emb * KB16 + b * HH + u);
            __hip_atomic_store(dst, __float_as_uint(h), __ATOMIC_RELAXED,
                               __HIP_MEMORY_SCOPE_AGENT);
        }
    }
}

// ---------------------------------------------------------------------------
// scores[t,b,s] = feats . W_lin[s] + b_lin[s], feats = [hsTf | hsTb] along k.
// h layout now [t][b][k]: A-staging transposes to As[k][b] (same pattern as
// the W_lin staging). One block per t.
// ---------------------------------------------------------------------------
__global__ __launch_bounds__(256) void scores_kernel(
    const float* __restrict__ hsTf, const float* __restrict__ hsTb,
    const float* __restrict__ W_lin, const float* __restrict__ b_lin,
    float* __restrict__ scores)
{
    __shared__ float As[128 * 64];   // As[k][b]
    __shared__ float Ws[128 * 64];   // Ws[k][s]
    const int t   = blockIdx.x;
    const int tid = threadIdx.x;
    const int bl  = tid & 63;
    const int kc  = tid >> 6;        // 0..3
    const int tb  = tid & 15;
    const int ts  = tid >> 4;

    float acc[4][4] = {};

    for (int chunk = 0; chunk < 4; ++chunk) {
        const int koff = chunk * 128;
        const float* srcA = (koff < 256)
            ? (hsTf + (size_t)t * KB16 + (koff & 255))
            : (hsTb + (size_t)t * KB16 + (koff & 255));
        const float4* sa4 = (const float4*)srcA;      // row pitch 64 f4 (256 fl)
        #pragma unroll
        for (int it = 0; it < 8; ++it) {
            const int k4 = it * 4 + kc;               // 0..31
            float4 av = sa4[bl * 64 + k4];
            const int k = k4 * 4;
            As[(k + 0) * 64 + bl] = av.x; As[(k + 1) * 64 + bl] = av.y;
            As[(k + 2) * 64 + bl] = av.z; As[(k + 3) * 64 + bl] = av.w;
        }
        const float4* wl4 = (const float4*)(W_lin + koff);  // row pitch 128 f4
        #pragma unroll
        for (int it = 0; it < 8; ++it) {
            const int k4 = it * 4 + kc;
            float4 wv = wl4[bl * 128 + k4];
            const int k = k4 * 4;
            Ws[(k + 0) * 64 + bl] = wv.x; Ws[(k + 1) * 64 + bl] = wv.y;
            Ws[(k + 2) * 64 + bl] = wv.z; Ws[(k + 3) * 64 + bl] = wv.w;
        }
        __syncthreads();
        #pragma unroll 4
        for (int k = 0; k < 128; ++k) {
            const float4 av = *(const float4*)&As[k * 64 + tb * 4];
            const float4 bv = *(const float4*)&Ws[k * 64 + ts * 4];
            acc[0][0] += av.x * bv.x; acc[0][1] += av.x * bv.y; acc[0][2] += av.x * bv.z; acc[0][3] += av.x * bv.w;
            acc[1][0] += av.y * bv.x; acc[1][1] += av.y * bv.y; acc[1][2] += av.y * bv.z; acc[1][3] += av.y * bv.w;
            acc[2][0] += av.z * bv.x; acc[2][1] += av.z * bv.y; acc[2][2] += av.z * bv.z; acc[2][3] += av.z * bv.w;
            acc[3][0] += av.w * bv.x; acc[3][1] += av.w * bv.y; acc[3][2] += av.w * bv.z; acc[3][3] += av.w * bv.w;
        }
        __syncthreads();
    }

    #pragma unroll
    for (int i = 0; i < 4; ++i) {
        const int bb = tb * 4 + i;
        #pragma unroll
        for (int j = 0; j < 4; ++j) {
            const int ss = ts * 4 + j;
            scores[(size_t)t * (BB * SS) + bb * SS + ss] = acc[i][j] + b_lin[ss];
        }
    }
}

// ---------------------------------------------------------------------------
// Viterbi forward + backtrace. One block per batch b; 256 threads:
// thread (s = tid&63, q = tid>>6) scans prev-states p in [q*16,(q+1)*16).
// Ascending strict-'>' scan + ascending combine == numpy first-index argmax.
// ---------------------------------------------------------------------------
__global__ __launch_bounds__(256) void viterbi_kernel(
    const float* __restrict__ scores, const float* __restrict__ pairwise,
    const float* __restrict__ start, const float* __restrict__ stop,
    float* __restrict__ out)
{
    __shared__ float delta[2][64];
    __shared__ float part[4][64];
    __shared__ int   pidx[4][64];
    __shared__ unsigned char bps[511 * 64];
    __shared__ float fin[64];

    const int b   = blockIdx.x;
    const int tid = threadIdx.x;
    const int s   = tid & 63;
    const int q   = tid >> 6;

    float pw[16];
    #pragma unroll
    for (int i = 0; i < 16; ++i)
        pw[i] = pairwise[(q * 16 + i) * 64 + s];

    if (q == 0) delta[0][s] = start[s] + scores[b * SS + s];
    __syncthreads();

    int cur = 0;
    for (int t = 1; t < TT; ++t) {
        float sc = 0.0f;
        if (q == 0) sc = scores[(size_t)t * (BB * SS) + b * SS + s];
        float best = -1e30f;
        int bp = q * 16;
        #pragma unroll
        for (int i = 0; i < 16; ++i) {
            const float v = delta[cur][q * 16 + i] + pw[i];   // broadcast read
            if (v > best) { best = v; bp = q * 16 + i; }
        }
        part[q][s] = best;
        pidx[q][s] = bp;
        __syncthreads();
        if (q == 0) {
            float m = part[0][s];
            int arg = pidx[0][s];
            #pragma unroll
            for (int qq = 1; qq < 4; ++qq) {
                const float v = part[qq][s];
                if (v > m) { m = v; arg = pidx[qq][s]; }
            }
            delta[cur ^ 1][s] = m + sc;
            bps[(t - 1) * 64 + s] = (unsigned char)arg;
        }
        cur ^= 1;
        __syncthreads();
    }

    if (q == 0) fin[s] = delta[cur][s] + stop[s];
    __syncthreads();

    if (tid == 0) {
        float m = fin[0];
        int arg = 0;
        for (int p = 1; p < 64; ++p)
            if (fin[p] > m) { m = fin[p]; arg = p; }
        out[b] = m;
        int st = arg;
        out[64 + 511 * 64 + b] = (float)st;
        for (int k = 510; k >= 0; --k) {
            st = bps[k * 64 + st];
            out[64 + k * 64 + b] = (float)st;
        }
    }
}

// ---------------------------------------------------------------------------
extern "C" void kernel_launch(void* const* d_in, const int* in_sizes, int n_in,
                              void* d_out, int out_size, void* d_ws, size_t ws_size,
                              hipStream_t stream)
{
    const int*   obs      = (const int*)d_in[0];
    const float* h0       = (const float*)d_in[1];
    const float* c0       = (const float*)d_in[2];
    const float* embed    = (const float*)d_in[3];
    const float* Wih_f    = (const float*)d_in[4];
    const float* Whh_f    = (const float*)d_in[5];
    const float* bih_f    = (const float*)d_in[6];
    const float* bhh_f    = (const float*)d_in[7];
    const float* Wih_b    = (const float*)d_in[8];
    const float* Whh_b    = (const float*)d_in[9];
    const float* bih_b    = (const float*)d_in[10];
    const float* bhh_b    = (const float*)d_in[11];
    const float* W_lin    = (const float*)d_in[12];
    const float* b_lin    = (const float*)d_in[13];
    const float* pairwise = (const float*)d_in[14];
    const float* start    = (const float*)d_in[15];
    const float* stop     = (const float*)d_in[16];
    (void)in_sizes; (void)n_in; (void)out_size; (void)ws_size;

    // ws layout (floats): embT | hsTf | hsTb | scores   (~104 MB)
    float* ws     = (float*)d_ws;
    float* embT   = ws;
    float* hsTf   = embT + (size_t)TT * KB16;
    float* hsTb   = hsTf + (size_t)TT * KB16;
    float* scores = hsTb + (size_t)TT * KB16;

    // sentinel-init hsTf+hsTb (contiguous, 64 MB): 0xFF bytes = float NaN
    hipMemsetAsync(hsTf, 0xFF, (size_t)2 * TT * KB16 * sizeof(float), stream);
    embT_prep<<<512, 256, 0, stream>>>(obs, embed, embT);
    lstm_persist<<<256, 512, 0, stream>>>(
        embT, Wih_f, Whh_f, bih_f, bhh_f, Wih_b, Whh_b, bih_b, bhh_b,
        h0, c0, hsTf, hsTb);
    scores_kernel<<<512, 256, 0, stream>>>(hsTf, hsTb, W_lin, b_lin, scores);
    viterbi_kernel<<<64, 256, 0, stream>>>(scores, pairwise, start, stop, (float*)d_out);
}

// Round 8
// 3083.694 us; speedup vs baseline: 1.5469x; 1.5469x over previous
//
#include <hip/hip_runtime.h>
#include <math.h>

// Problem constants
constexpr int TT = 512;   // sequence length
constexpr int BB = 64;    // batch
constexpr int EE = 256;   // embed dim
constexpr int HH = 256;   // hidden
constexpr int SS = 64;    // states
constexpr int BH = BB * HH;       // 16384
constexpr int KB16 = HH * BB;     // floats per t-slice (16384)

// ---------------------------------------------------------------------------
// embT[t][k][b] = embed[obs[t][b]][k]  (transposed embedding sequence)
// ---------------------------------------------------------------------------
__global__ __launch_bounds__(256) void embT_prep(
    const int* __restrict__ obs, const float* __restrict__ embed,
    float* __restrict__ embT)
{
    const int t   = blockIdx.x;
    const int tid = threadIdx.x;
    const int b   = tid & 63;
    const int kc  = tid >> 6;                       // 0..3
    const int tok = obs[t * BB + b];
    const float4* er = (const float4*)(embed + (size_t)tok * EE);
    float* dst = embT + (size_t)t * KB16;
    #pragma unroll
    for (int i = 0; i < 16; ++i) {
        const int k4 = kc * 16 + i;
        float4 v = er[k4];
        const int k = k4 * 4;
        dst[(k + 0) * 64 + b] = v.x;
        dst[(k + 1) * 64 + b] = v.y;
        dst[(k + 2) * 64 + b] = v.z;
        dst[(k + 3) * 64 + b] = v.w;
    }
}

// ---------------------------------------------------------------------------
// Persistent BiLSTM recurrence, dataflow-synchronized (poll-on-data).
// Grid 256 = 2 dirs x 128 ublocks; 512 threads (8 waves); all blocks
// co-resident; bounded poll guarantees termination regardless.
// h layout hsT[t][k][b]: producer stores are two fully-coalesced 256B lines
// per block (R6's [t][b][u] layout caused 8x HBM write amplification, 512MB);
// consumer reads are wave-coalesced (64 lanes x dword = 256B per k).
// Poll = two volatile asm statements (16 global_load_dword each, ONE base
// register + immediate offsets k*256 <= 3840) + single vmcnt(0): one L3
// round trip per poll iteration, compile-safe operand count (R4's 32
// independent address operands broke the build).
// Sentinel = 0xFF bytes (float NaN pattern, unreachable for h=o*tanh(c)).
// FMA order: x k-ascending then h k-ascending (= R3, bit-exact).
// ---------------------------------------------------------------------------
__global__ __launch_bounds__(512, 2) void lstm_persist(
    const float* __restrict__ embT,
    const float* __restrict__ Wih_f, const float* __restrict__ Whh_f,
    const float* __restrict__ bih_f, const float* __restrict__ bhh_f,
    const float* __restrict__ Wih_b, const float* __restrict__ Whh_b,
    const float* __restrict__ bih_b, const float* __restrict__ bhh_b,
    const float* __restrict__ h0, const float* __restrict__ c0,
    float* __restrict__ hsTf, float* __restrict__ hsTb)
{
    __shared__ float buf[8192];    // 32 KB: double-buffered partial exchange
    const int tid  = threadIdx.x;
    const int b    = tid & 63;
    const int w    = tid >> 6;     // 0..7 K-chunk index
    const int bx   = blockIdx.x;
    const int dir  = bx & 1;
    const int ublk = bx >> 1;      // 0..127
    const int u0   = ublk * 2;

    const float* Wih = dir ? Wih_b : Wih_f;
    const float* Whh = dir ? Whh_b : Whh_f;
    const float* bih = dir ? bih_b : bih_f;
    const float* bhh = dir ? bhh_b : bhh_f;
    float* hsT = dir ? hsTb : hsTf;

    const int kbase = w * 32;
    const int kb_s  = __builtin_amdgcn_readfirstlane(kbase);

    // 8 gate-row weight bases (wave-uniform -> scalar K$ loads)
    const float* Wx0 = Wih + (size_t)(0 * 256 + u0    ) * EE + kb_s;
    const float* Wx1 = Wih + (size_t)(0 * 256 + u0 + 1) * EE + kb_s;
    const float* Wx2 = Wih + (size_t)(1 * 256 + u0    ) * EE + kb_s;
    const float* Wx3 = Wih + (size_t)(1 * 256 + u0 + 1) * EE + kb_s;
    const float* Wx4 = Wih + (size_t)(2 * 256 + u0    ) * EE + kb_s;
    const float* Wx5 = Wih + (size_t)(2 * 256 + u0 + 1) * EE + kb_s;
    const float* Wx6 = Wih + (size_t)(3 * 256 + u0    ) * EE + kb_s;
    const float* Wx7 = Wih + (size_t)(3 * 256 + u0 + 1) * EE + kb_s;
    const float* Wh0 = Whh + (size_t)(0 * 256 + u0    ) * HH + kb_s;
    const float* Wh1 = Whh + (size_t)(0 * 256 + u0 + 1) * HH + kb_s;
    const float* Wh2 = Whh + (size_t)(1 * 256 + u0    ) * HH + kb_s;
    const float* Wh3 = Whh + (size_t)(1 * 256 + u0 + 1) * HH + kb_s;
    const float* Wh4 = Whh + (size_t)(2 * 256 + u0    ) * HH + kb_s;
    const float* Wh5 = Whh + (size_t)(2 * 256 + u0 + 1) * HH + kb_s;
    const float* Wh6 = Whh + (size_t)(3 * 256 + u0    ) * HH + kb_s;
    const float* Wh7 = Whh + (size_t)(3 * 256 + u0 + 1) * HH + kb_s;

    // persistent cell state + biases (tid<128: uo = tid>>6, unit u0+uo)
    float c_reg = 0.0f;
    float bias0 = 0.f, bias1 = 0.f, bias2 = 0.f, bias3 = 0.f;
    if (tid < 128) {
        const int uo = tid >> 6;
        const int u  = u0 + uo;
        c_reg = c0[dir * BH + b * HH + u];
        bias0 = bih[0 * 256 + u] + bhh[0 * 256 + u];
        bias1 = bih[1 * 256 + u] + bhh[1 * 256 + u];
        bias2 = bih[2 * 256 + u] + bhh[2 * 256 + u];
        bias3 = bih[3 * 256 + u] + bhh[3 * 256 + u];
    }

    for (int step = 0; step < TT; ++step) {
        const int t_emb = dir ? (TT - 1 - step) : step;

        float acc0 = 0.f, acc1 = 0.f, acc2 = 0.f, acc3 = 0.f;
        float acc4 = 0.f, acc5 = 0.f, acc6 = 0.f, acc7 = 0.f;

        // ---- x dots first (no h dependency; covers producer lag) ----
        {
            const float* xs = embT + (size_t)t_emb * KB16 + kbase * 64 + b;
            #pragma unroll 8
            for (int k = 0; k < 32; ++k) {
                const float x = xs[k * 64];
                acc0 = fmaf(x, Wx0[k], acc0);
                acc1 = fmaf(x, Wx1[k], acc1);
                acc2 = fmaf(x, Wx2[k], acc2);
                acc3 = fmaf(x, Wx3[k], acc3);
                acc4 = fmaf(x, Wx4[k], acc4);
                acc5 = fmaf(x, Wx5[k], acc5);
                acc6 = fmaf(x, Wx6[k], acc6);
                acc7 = fmaf(x, Wx7[k], acc7);
            }
        }

        // ---- h values: poll-on-data, batched one-round-trip loads ----
        float hv[32];
        if (step == 0) {
            const float* hp = h0 + dir * BH + b * HH + kbase;  // contiguous
            #pragma unroll
            for (int k = 0; k < 32; ++k) hv[k] = hp[k];
        } else {
            const int t_prev = dir ? (t_emb + 1) : (t_emb - 1);
            const float* hsrc = hsT + (size_t)t_prev * KB16 + kbase * 64 + b;
            const float* hsrc2 = hsrc + 16 * 64;
            int spins = 0;
            for (;;) {
                asm volatile(
                    "global_load_dword %0, %16, off sc0 sc1\n\t"
                    "global_load_dword %1, %16, off offset:256 sc0 sc1\n\t"
                    "global_load_dword %2, %16, off offset:512 sc0 sc1\n\t"
                    "global_load_dword %3, %16, off offset:768 sc0 sc1\n\t"
                    "global_load_dword %4, %16, off offset:1024 sc0 sc1\n\t"
                    "global_load_dword %5, %16, off offset:1280 sc0 sc1\n\t"
                    "global_load_dword %6, %16, off offset:1536 sc0 sc1\n\t"
                    "global_load_dword %7, %16, off offset:1792 sc0 sc1\n\t"
                    "global_load_dword %8, %16, off offset:2048 sc0 sc1\n\t"
                    "global_load_dword %9, %16, off offset:2304 sc0 sc1\n\t"
                    "global_load_dword %10, %16, off offset:2560 sc0 sc1\n\t"
                    "global_load_dword %11, %16, off offset:2816 sc0 sc1\n\t"
                    "global_load_dword %12, %16, off offset:3072 sc0 sc1\n\t"
                    "global_load_dword %13, %16, off offset:3328 sc0 sc1\n\t"
                    "global_load_dword %14, %16, off offset:3584 sc0 sc1\n\t"
                    "global_load_dword %15, %16, off offset:3840 sc0 sc1"
                    : "=v"(hv[0]),  "=v"(hv[1]),  "=v"(hv[2]),  "=v"(hv[3]),
                      "=v"(hv[4]),  "=v"(hv[5]),  "=v"(hv[6]),  "=v"(hv[7]),
                      "=v"(hv[8]),  "=v"(hv[9]),  "=v"(hv[10]), "=v"(hv[11]),
                      "=v"(hv[12]), "=v"(hv[13]), "=v"(hv[14]), "=v"(hv[15])
                    : "v"(hsrc)
                    : "memory");
                asm volatile(
                    "global_load_dword %0, %16, off sc0 sc1\n\t"
                    "global_load_dword %1, %16, off offset:256 sc0 sc1\n\t"
                    "global_load_dword %2, %16, off offset:512 sc0 sc1\n\t"
                    "global_load_dword %3, %16, off offset:768 sc0 sc1\n\t"
                    "global_load_dword %4, %16, off offset:1024 sc0 sc1\n\t"
                    "global_load_dword %5, %16, off offset:1280 sc0 sc1\n\t"
                    "global_load_dword %6, %16, off offset:1536 sc0 sc1\n\t"
                    "global_load_dword %7, %16, off offset:1792 sc0 sc1\n\t"
                    "global_load_dword %8, %16, off offset:2048 sc0 sc1\n\t"
                    "global_load_dword %9, %16, off offset:2304 sc0 sc1\n\t"
                    "global_load_dword %10, %16, off offset:2560 sc0 sc1\n\t"
                    "global_load_dword %11, %16, off offset:2816 sc0 sc1\n\t"
                    "global_load_dword %12, %16, off offset:3072 sc0 sc1\n\t"
                    "global_load_dword %13, %16, off offset:3328 sc0 sc1\n\t"
                    "global_load_dword %14, %16, off offset:3584 sc0 sc1\n\t"
                    "global_load_dword %15, %16, off offset:3840 sc0 sc1\n\t"
                    "s_waitcnt vmcnt(0)"
                    : "=v"(hv[16]), "=v"(hv[17]), "=v"(hv[18]), "=v"(hv[19]),
                      "=v"(hv[20]), "=v"(hv[21]), "=v"(hv[22]), "=v"(hv[23]),
                      "=v"(hv[24]), "=v"(hv[25]), "=v"(hv[26]), "=v"(hv[27]),
                      "=v"(hv[28]), "=v"(hv[29]), "=v"(hv[30]), "=v"(hv[31])
                    : "v"(hsrc2)
                    : "memory");
                unsigned bad = 0;
                #pragma unroll
                for (int k = 0; k < 32; ++k)
                    bad |= (__float_as_uint(hv[k]) == 0xFFFFFFFFu);
                if (!__any(bad)) break;
                if (++spins > 16384) break;   // hard termination guarantee
                __builtin_amdgcn_s_sleep(1);
            }
        }

        // ---- h dots ----
        #pragma unroll 8
        for (int k = 0; k < 32; ++k) {
            const float h = hv[k];
            acc0 = fmaf(h, Wh0[k], acc0);
            acc1 = fmaf(h, Wh1[k], acc1);
            acc2 = fmaf(h, Wh2[k], acc2);
            acc3 = fmaf(h, Wh3[k], acc3);
            acc4 = fmaf(h, Wh4[k], acc4);
            acc5 = fmaf(h, Wh5[k], acc5);
            acc6 = fmaf(h, Wh6[k], acc6);
            acc7 = fmaf(h, Wh7[k], acc7);
        }

        // ---- exchange partials: pb[w][dot], dot = r*64 + b (double-buffered) ----
        float* pb = buf + ((step & 1) << 12);
        pb[w * 512 + 0 * 64 + b] = acc0;
        pb[w * 512 + 1 * 64 + b] = acc1;
        pb[w * 512 + 2 * 64 + b] = acc2;
        pb[w * 512 + 3 * 64 + b] = acc3;
        pb[w * 512 + 4 * 64 + b] = acc4;
        pb[w * 512 + 5 * 64 + b] = acc5;
        pb[w * 512 + 6 * 64 + b] = acc6;
        pb[w * 512 + 7 * 64 + b] = acc7;
        __syncthreads();   // the ONLY per-step block sync

        // ---- cell update (128 threads: b, uo); coalesced 256B-line store ----
        if (tid < 128) {
            const int uo = tid >> 6;
            const int u  = u0 + uo;
            float p0 = bias0, p1 = bias1, p2 = bias2, p3 = bias3;
            #pragma unroll
            for (int ww = 0; ww < 8; ++ww) {
                p0 += pb[ww * 512 + (0 * 2 + uo) * 64 + b];
                p1 += pb[ww * 512 + (1 * 2 + uo) * 64 + b];
                p2 += pb[ww * 512 + (2 * 2 + uo) * 64 + b];
                p3 += pb[ww * 512 + (3 * 2 + uo) * 64 + b];
            }
            const float ig = 1.0f / (1.0f + expf(-p0));
            const float fg = 1.0f / (1.0f + expf(-p1));
            const float gg = tanhf(p2);
            const float og = 1.0f / (1.0f + expf(-p3));
            c_reg = fg * c_reg + ig * gg;
            const float h = og * tanhf(c_reg);
            unsigned* dst = (unsigned*)(hsT + (size_t)t_emb * KB16 + u * 64 + b);
            __hip_atomic_store(dst, __float_as_uint(h), __ATOMIC_RELAXED,
                               __HIP_MEMORY_SCOPE_AGENT);
        }
    }
}

// ---------------------------------------------------------------------------
// scores[t,b,s] = sum_k hsTf[t][k][b]*W_lin[s][k] + hsTb[t][k][b]*W_lin[s][256+k]
//                 + b_lin[s].  One block per t.
// ---------------------------------------------------------------------------
__global__ __launch_bounds__(256) void scores_kernel(
    const float* __restrict__ hsTf, const float* __restrict__ hsTb,
    const float* __restrict__ W_lin, const float* __restrict__ b_lin,
    float* __restrict__ scores)
{
    __shared__ float As[128 * 64];   // As[k][b]
    __shared__ float Ws[128 * 64];   // Ws[k][s]
    const int t   = blockIdx.x;
    const int tid = threadIdx.x;
    const int bl  = tid & 63;
    const int kc  = tid >> 6;        // 0..3
    const int tb  = tid & 15;
    const int ts  = tid >> 4;

    float acc[4][4] = {};

    for (int chunk = 0; chunk < 4; ++chunk) {
        const int koff = chunk * 128;
        const float* srcA = (koff < 256)
            ? (hsTf + (size_t)t * KB16 + (size_t)koff * 64)
            : (hsTb + (size_t)t * KB16 + (size_t)(koff - 256) * 64);
        const float4* sA4 = (const float4*)srcA;
        float4* As4 = (float4*)As;
        #pragma unroll
        for (int i = 0; i < 8; ++i) As4[tid + i * 256] = sA4[tid + i * 256];
        const float4* wl4 = (const float4*)(W_lin + koff);  // row pitch 128 f4
        #pragma unroll
        for (int it = 0; it < 8; ++it) {
            const int k4 = it * 4 + kc;
            float4 wv = wl4[bl * 128 + k4];
            const int k = k4 * 4;
            Ws[(k + 0) * 64 + bl] = wv.x; Ws[(k + 1) * 64 + bl] = wv.y;
            Ws[(k + 2) * 64 + bl] = wv.z; Ws[(k + 3) * 64 + bl] = wv.w;
        }
        __syncthreads();
        #pragma unroll 4
        for (int k = 0; k < 128; ++k) {
            const float4 av = *(const float4*)&As[k * 64 + tb * 4];
            const float4 bv = *(const float4*)&Ws[k * 64 + ts * 4];
            acc[0][0] += av.x * bv.x; acc[0][1] += av.x * bv.y; acc[0][2] += av.x * bv.z; acc[0][3] += av.x * bv.w;
            acc[1][0] += av.y * bv.x; acc[1][1] += av.y * bv.y; acc[1][2] += av.y * bv.z; acc[1][3] += av.y * bv.w;
            acc[2][0] += av.z * bv.x; acc[2][1] += av.z * bv.y; acc[2][2] += av.z * bv.z; acc[2][3] += av.z * bv.w;
            acc[3][0] += av.w * bv.x; acc[3][1] += av.w * bv.y; acc[3][2] += av.w * bv.z; acc[3][3] += av.w * bv.w;
        }
        __syncthreads();
    }

    #pragma unroll
    for (int i = 0; i < 4; ++i) {
        const int bb = tb * 4 + i;
        #pragma unroll
        for (int j = 0; j < 4; ++j) {
            const int ss = ts * 4 + j;
            scores[(size_t)t * (BB * SS) + bb * SS + ss] = acc[i][j] + b_lin[ss];
        }
    }
}

// ---------------------------------------------------------------------------
// Viterbi forward + backtrace. One block per batch b; 256 threads:
// thread (s = tid&63, q = tid>>6) scans prev-states p in [q*16,(q+1)*16).
// Ascending strict-'>' scan + ascending combine == numpy first-index argmax.
// ---------------------------------------------------------------------------
__global__ __launch_bounds__(256) void viterbi_kernel(
    const float* __restrict__ scores, const float* __restrict__ pairwise,
    const float* __restrict__ start, const float* __restrict__ stop,
    float* __restrict__ out)
{
    __shared__ float delta[2][64];
    __shared__ float part[4][64];
    __shared__ int   pidx[4][64];
    __shared__ unsigned char bps[511 * 64];
    __shared__ float fin[64];

    const int b   = blockIdx.x;
    const int tid = threadIdx.x;
    const int s   = tid & 63;
    const int q   = tid >> 6;

    float pw[16];
    #pragma unroll
    for (int i = 0; i < 16; ++i)
        pw[i] = pairwise[(q * 16 + i) * 64 + s];

    if (q == 0) delta[0][s] = start[s] + scores[b * SS + s];
    __syncthreads();

    int cur = 0;
    for (int t = 1; t < TT; ++t) {
        float sc = 0.0f;
        if (q == 0) sc = scores[(size_t)t * (BB * SS) + b * SS + s];
        float best = -1e30f;
        int bp = q * 16;
        #pragma unroll
        for (int i = 0; i < 16; ++i) {
            const float v = delta[cur][q * 16 + i] + pw[i];   // broadcast read
            if (v > best) { best = v; bp = q * 16 + i; }
        }
        part[q][s] = best;
        pidx[q][s] = bp;
        __syncthreads();
        if (q == 0) {
            float m = part[0][s];
            int arg = pidx[0][s];
            #pragma unroll
            for (int qq = 1; qq < 4; ++qq) {
                const float v = part[qq][s];
                if (v > m) { m = v; arg = pidx[qq][s]; }
            }
            delta[cur ^ 1][s] = m + sc;
            bps[(t - 1) * 64 + s] = (unsigned char)arg;
        }
        cur ^= 1;
        __syncthreads();
    }

    if (q == 0) fin[s] = delta[cur][s] + stop[s];
    __syncthreads();

    if (tid == 0) {
        float m = fin[0];
        int arg = 0;
        for (int p = 1; p < 64; ++p)
            if (fin[p] > m) { m = fin[p]; arg = p; }
        out[b] = m;
        int st = arg;
        out[64 + 511 * 64 + b] = (float)st;
        for (int k = 510; k >= 0; --k) {
            st = bps[k * 64 + st];
            out[64 + k * 64 + b] = (float)st;
        }
    }
}

// ---------------------------------------------------------------------------
extern "C" void kernel_launch(void* const* d_in, const int* in_sizes, int n_in,
                              void* d_out, int out_size, void* d_ws, size_t ws_size,
                              hipStream_t stream)
{
    const int*   obs      = (const int*)d_in[0];
    const float* h0       = (const float*)d_in[1];
    const float* c0       = (const float*)d_in[2];
    const float* embed    = (const float*)d_in[3];
    const float* Wih_f    = (const float*)d_in[4];
    const float* Whh_f    = (const float*)d_in[5];
    const float* bih_f    = (const float*)d_in[6];
    const float* bhh_f    = (const float*)d_in[7];
    const float* Wih_b    = (const float*)d_in[8];
    const float* Whh_b    = (const float*)d_in[9];
    const float* bih_b    = (const float*)d_in[10];
    const float* bhh_b    = (const float*)d_in[11];
    const float* W_lin    = (const float*)d_in[12];
    const float* b_lin    = (const float*)d_in[13];
    const float* pairwise = (const float*)d_in[14];
    const float* start    = (const float*)d_in[15];
    const float* stop     = (const float*)d_in[16];
    (void)in_sizes; (void)n_in; (void)out_size; (void)ws_size;

    // ws layout (floats): embT | hsTf | hsTb | scores   (~104 MB)
    float* ws     = (float*)d_ws;
    float* embT   = ws;
    float* hsTf   = embT + (size_t)TT * KB16;
    float* hsTb   = hsTf + (size_t)TT * KB16;
    float* scores = hsTb + (size_t)TT * KB16;

    // sentinel-init hsTf+hsTb (contiguous, 64 MB): 0xFF bytes = float NaN
    hipMemsetAsync(hsTf, 0xFF, (size_t)2 * TT * KB16 * sizeof(float), stream);
    embT_prep<<<512, 256, 0, stream>>>(obs, embed, embT);
    lstm_persist<<<256, 512, 0, stream>>>(
        embT, Wih_f, Whh_f, bih_f, bhh_f, Wih_b, Whh_b, bih_b, bhh_b,
        h0, c0, hsTf, hsTb);
    scores_kernel<<<512, 256, 0, stream>>>(hsTf, hsTb, W_lin, b_lin, scores);
    viterbi_kernel<<<64, 256, 0, stream>>>(scores, pairwise, start, stop, (float*)d_out);
}

// Round 9
// 2988.439 us; speedup vs baseline: 1.5963x; 1.0319x over previous
//
#include <hip/hip_runtime.h>
#include <math.h>

// Problem constants
constexpr int TT = 512;   // sequence length
constexpr int BB = 64;    // batch
constexpr int EE = 256;   // embed dim
constexpr int HH = 256;   // hidden
constexpr int SS = 64;    // states
constexpr int BH = BB * HH;       // 16384
constexpr int KB16 = HH * BB;     // floats per t-slice (16384)

// ---------------------------------------------------------------------------
// embT[t][k][b] = embed[obs[t][b]][k]  (transposed embedding sequence)
// ---------------------------------------------------------------------------
__global__ __launch_bounds__(256) void embT_prep(
    const int* __restrict__ obs, const float* __restrict__ embed,
    float* __restrict__ embT)
{
    const int t   = blockIdx.x;
    const int tid = threadIdx.x;
    const int b   = tid & 63;
    const int kc  = tid >> 6;                       // 0..3
    const int tok = obs[t * BB + b];
    const float4* er = (const float4*)(embed + (size_t)tok * EE);
    float* dst = embT + (size_t)t * KB16;
    #pragma unroll
    for (int i = 0; i < 16; ++i) {
        const int k4 = kc * 16 + i;
        float4 v = er[k4];
        const int k = k4 * 4;
        dst[(k + 0) * 64 + b] = v.x;
        dst[(k + 1) * 64 + b] = v.y;
        dst[(k + 2) * 64 + b] = v.z;
        dst[(k + 3) * 64 + b] = v.w;
    }
}

// ---------------------------------------------------------------------------
// Persistent BiLSTM recurrence, dataflow-synchronized (poll-on-data).
// Grid 256 = 2 dirs x 128 ublocks; 512 threads (8 waves); all co-resident;
// bounded poll guarantees termination regardless.
// h layout hsT[t][k][b]: coalesced 256B-line producer stores, wave-coalesced
// consumer reads. Poll = two asm statements (16 global_load_dword each, one
// base reg + imm offsets) + single vmcnt(0): one L3 round trip / iteration.
// R8 changes vs R7:
//  * producer h-store is an agent-scope atomic EXCHANGE -> executes at the
//    Infinity-Cache coherence point: visible to other XCDs immediately
//    (plain relaxed stores can linger pre-writeback in the local L2).
//  * hot spin (no s_sleep) -> no 64-cyc detection quantization.
//  * sentinel check via NaN-propagating sum (31 adds + 1 cmp vs 64 ops).
// Sentinel = 0xFF bytes (NaN), unreachable for h = o*tanh(c) (|h|<1, finite).
// FMA order: x k-ascending then h k-ascending (= R3/R7, bit-exact).
// ---------------------------------------------------------------------------
__global__ __launch_bounds__(512, 2) void lstm_persist(
    const float* __restrict__ embT,
    const float* __restrict__ Wih_f, const float* __restrict__ Whh_f,
    const float* __restrict__ bih_f, const float* __restrict__ bhh_f,
    const float* __restrict__ Wih_b, const float* __restrict__ Whh_b,
    const float* __restrict__ bih_b, const float* __restrict__ bhh_b,
    const float* __restrict__ h0, const float* __restrict__ c0,
    float* __restrict__ hsTf, float* __restrict__ hsTb)
{
    __shared__ float buf[8192];    // 32 KB: double-buffered partial exchange
    const int tid  = threadIdx.x;
    const int b    = tid & 63;
    const int w    = tid >> 6;     // 0..7 K-chunk index
    const int bx   = blockIdx.x;
    const int dir  = bx & 1;
    const int ublk = bx >> 1;      // 0..127
    const int u0   = ublk * 2;

    const float* Wih = dir ? Wih_b : Wih_f;
    const float* Whh = dir ? Whh_b : Whh_f;
    const float* bih = dir ? bih_b : bih_f;
    const float* bhh = dir ? bhh_b : bhh_f;
    float* hsT = dir ? hsTb : hsTf;

    const int kbase = w * 32;
    const int kb_s  = __builtin_amdgcn_readfirstlane(kbase);

    // 8 gate-row weight bases (wave-uniform -> scalar K$ loads)
    const float* Wx0 = Wih + (size_t)(0 * 256 + u0    ) * EE + kb_s;
    const float* Wx1 = Wih + (size_t)(0 * 256 + u0 + 1) * EE + kb_s;
    const float* Wx2 = Wih + (size_t)(1 * 256 + u0    ) * EE + kb_s;
    const float* Wx3 = Wih + (size_t)(1 * 256 + u0 + 1) * EE + kb_s;
    const float* Wx4 = Wih + (size_t)(2 * 256 + u0    ) * EE + kb_s;
    const float* Wx5 = Wih + (size_t)(2 * 256 + u0 + 1) * EE + kb_s;
    const float* Wx6 = Wih + (size_t)(3 * 256 + u0    ) * EE + kb_s;
    const float* Wx7 = Wih + (size_t)(3 * 256 + u0 + 1) * EE + kb_s;
    const float* Wh0 = Whh + (size_t)(0 * 256 + u0    ) * HH + kb_s;
    const float* Wh1 = Whh + (size_t)(0 * 256 + u0 + 1) * HH + kb_s;
    const float* Wh2 = Whh + (size_t)(1 * 256 + u0    ) * HH + kb_s;
    const float* Wh3 = Whh + (size_t)(1 * 256 + u0 + 1) * HH + kb_s;
    const float* Wh4 = Whh + (size_t)(2 * 256 + u0    ) * HH + kb_s;
    const float* Wh5 = Whh + (size_t)(2 * 256 + u0 + 1) * HH + kb_s;
    const float* Wh6 = Whh + (size_t)(3 * 256 + u0    ) * HH + kb_s;
    const float* Wh7 = Whh + (size_t)(3 * 256 + u0 + 1) * HH + kb_s;

    // persistent cell state + biases (tid<128: uo = tid>>6, unit u0+uo)
    float c_reg = 0.0f;
    float bias0 = 0.f, bias1 = 0.f, bias2 = 0.f, bias3 = 0.f;
    if (tid < 128) {
        const int uo = tid >> 6;
        const int u  = u0 + uo;
        c_reg = c0[dir * BH + b * HH + u];
        bias0 = bih[0 * 256 + u] + bhh[0 * 256 + u];
        bias1 = bih[1 * 256 + u] + bhh[1 * 256 + u];
        bias2 = bih[2 * 256 + u] + bhh[2 * 256 + u];
        bias3 = bih[3 * 256 + u] + bhh[3 * 256 + u];
    }

    for (int step = 0; step < TT; ++step) {
        const int t_emb = dir ? (TT - 1 - step) : step;

        float acc0 = 0.f, acc1 = 0.f, acc2 = 0.f, acc3 = 0.f;
        float acc4 = 0.f, acc5 = 0.f, acc6 = 0.f, acc7 = 0.f;

        // ---- x dots first (no h dependency; covers producer lag) ----
        {
            const float* xs = embT + (size_t)t_emb * KB16 + kbase * 64 + b;
            #pragma unroll 8
            for (int k = 0; k < 32; ++k) {
                const float x = xs[k * 64];
                acc0 = fmaf(x, Wx0[k], acc0);
                acc1 = fmaf(x, Wx1[k], acc1);
                acc2 = fmaf(x, Wx2[k], acc2);
                acc3 = fmaf(x, Wx3[k], acc3);
                acc4 = fmaf(x, Wx4[k], acc4);
                acc5 = fmaf(x, Wx5[k], acc5);
                acc6 = fmaf(x, Wx6[k], acc6);
                acc7 = fmaf(x, Wx7[k], acc7);
            }
        }

        // ---- h values: poll-on-data, batched one-round-trip loads ----
        float hv[32];
        if (step == 0) {
            const float* hp = h0 + dir * BH + b * HH + kbase;  // contiguous
            #pragma unroll
            for (int k = 0; k < 32; ++k) hv[k] = hp[k];
        } else {
            const int t_prev = dir ? (t_emb + 1) : (t_emb - 1);
            const float* hsrc = hsT + (size_t)t_prev * KB16 + kbase * 64 + b;
            const float* hsrc2 = hsrc + 16 * 64;
            int spins = 0;
            for (;;) {
                asm volatile(
                    "global_load_dword %0, %16, off sc0 sc1\n\t"
                    "global_load_dword %1, %16, off offset:256 sc0 sc1\n\t"
                    "global_load_dword %2, %16, off offset:512 sc0 sc1\n\t"
                    "global_load_dword %3, %16, off offset:768 sc0 sc1\n\t"
                    "global_load_dword %4, %16, off offset:1024 sc0 sc1\n\t"
                    "global_load_dword %5, %16, off offset:1280 sc0 sc1\n\t"
                    "global_load_dword %6, %16, off offset:1536 sc0 sc1\n\t"
                    "global_load_dword %7, %16, off offset:1792 sc0 sc1\n\t"
                    "global_load_dword %8, %16, off offset:2048 sc0 sc1\n\t"
                    "global_load_dword %9, %16, off offset:2304 sc0 sc1\n\t"
                    "global_load_dword %10, %16, off offset:2560 sc0 sc1\n\t"
                    "global_load_dword %11, %16, off offset:2816 sc0 sc1\n\t"
                    "global_load_dword %12, %16, off offset:3072 sc0 sc1\n\t"
                    "global_load_dword %13, %16, off offset:3328 sc0 sc1\n\t"
                    "global_load_dword %14, %16, off offset:3584 sc0 sc1\n\t"
                    "global_load_dword %15, %16, off offset:3840 sc0 sc1"
                    : "=v"(hv[0]),  "=v"(hv[1]),  "=v"(hv[2]),  "=v"(hv[3]),
                      "=v"(hv[4]),  "=v"(hv[5]),  "=v"(hv[6]),  "=v"(hv[7]),
                      "=v"(hv[8]),  "=v"(hv[9]),  "=v"(hv[10]), "=v"(hv[11]),
                      "=v"(hv[12]), "=v"(hv[13]), "=v"(hv[14]), "=v"(hv[15])
                    : "v"(hsrc)
                    : "memory");
                asm volatile(
                    "global_load_dword %0, %16, off sc0 sc1\n\t"
                    "global_load_dword %1, %16, off offset:256 sc0 sc1\n\t"
                    "global_load_dword %2, %16, off offset:512 sc0 sc1\n\t"
                    "global_load_dword %3, %16, off offset:768 sc0 sc1\n\t"
                    "global_load_dword %4, %16, off offset:1024 sc0 sc1\n\t"
                    "global_load_dword %5, %16, off offset:1280 sc0 sc1\n\t"
                    "global_load_dword %6, %16, off offset:1536 sc0 sc1\n\t"
                    "global_load_dword %7, %16, off offset:1792 sc0 sc1\n\t"
                    "global_load_dword %8, %16, off offset:2048 sc0 sc1\n\t"
                    "global_load_dword %9, %16, off offset:2304 sc0 sc1\n\t"
                    "global_load_dword %10, %16, off offset:2560 sc0 sc1\n\t"
                    "global_load_dword %11, %16, off offset:2816 sc0 sc1\n\t"
                    "global_load_dword %12, %16, off offset:3072 sc0 sc1\n\t"
                    "global_load_dword %13, %16, off offset:3328 sc0 sc1\n\t"
                    "global_load_dword %14, %16, off offset:3584 sc0 sc1\n\t"
                    "global_load_dword %15, %16, off offset:3840 sc0 sc1\n\t"
                    "s_waitcnt vmcnt(0)"
                    : "=v"(hv[16]), "=v"(hv[17]), "=v"(hv[18]), "=v"(hv[19]),
                      "=v"(hv[20]), "=v"(hv[21]), "=v"(hv[22]), "=v"(hv[23]),
                      "=v"(hv[24]), "=v"(hv[25]), "=v"(hv[26]), "=v"(hv[27]),
                      "=v"(hv[28]), "=v"(hv[29]), "=v"(hv[30]), "=v"(hv[31])
                    : "v"(hsrc2)
                    : "memory");
                // NaN-propagating sentinel check: valid h are finite (|h|<1),
                // sentinel bytes 0xFF are NaN -> sum is NaN iff any sentinel.
                float s = 0.0f;
                #pragma unroll
                for (int k = 0; k < 32; ++k) s += hv[k];
                if (!__any(s != s)) break;
                if (++spins > 16384) break;   // hard termination guarantee
                // hot spin: no s_sleep -> no 64-cyc detection quantization
            }
        }

        // ---- h dots ----
        #pragma unroll 8
        for (int k = 0; k < 32; ++k) {
            const float h = hv[k];
            acc0 = fmaf(h, Wh0[k], acc0);
            acc1 = fmaf(h, Wh1[k], acc1);
            acc2 = fmaf(h, Wh2[k], acc2);
            acc3 = fmaf(h, Wh3[k], acc3);
            acc4 = fmaf(h, Wh4[k], acc4);
            acc5 = fmaf(h, Wh5[k], acc5);
            acc6 = fmaf(h, Wh6[k], acc6);
            acc7 = fmaf(h, Wh7[k], acc7);
        }

        // ---- exchange partials: pb[w][dot], dot = r*64 + b (double-buffered) ----
        float* pb = buf + ((step & 1) << 12);
        pb[w * 512 + 0 * 64 + b] = acc0;
        pb[w * 512 + 1 * 64 + b] = acc1;
        pb[w * 512 + 2 * 64 + b] = acc2;
        pb[w * 512 + 3 * 64 + b] = acc3;
        pb[w * 512 + 4 * 64 + b] = acc4;
        pb[w * 512 + 5 * 64 + b] = acc5;
        pb[w * 512 + 6 * 64 + b] = acc6;
        pb[w * 512 + 7 * 64 + b] = acc7;
        __syncthreads();   // the ONLY per-step block sync

        // ---- cell update (128 threads: b, uo); coalesced 256B-line store ----
        if (tid < 128) {
            const int uo = tid >> 6;
            const int u  = u0 + uo;
            float p0 = bias0, p1 = bias1, p2 = bias2, p3 = bias3;
            #pragma unroll
            for (int ww = 0; ww < 8; ++ww) {
                p0 += pb[ww * 512 + (0 * 2 + uo) * 64 + b];
                p1 += pb[ww * 512 + (1 * 2 + uo) * 64 + b];
                p2 += pb[ww * 512 + (2 * 2 + uo) * 64 + b];
                p3 += pb[ww * 512 + (3 * 2 + uo) * 64 + b];
            }
            const float ig = 1.0f / (1.0f + expf(-p0));
            const float fg = 1.0f / (1.0f + expf(-p1));
            const float gg = tanhf(p2);
            const float og = 1.0f / (1.0f + expf(-p3));
            c_reg = fg * c_reg + ig * gg;
            const float h = og * tanhf(c_reg);
            unsigned* dst = (unsigned*)(hsT + (size_t)t_emb * KB16 + u * 64 + b);
            // atomic exchange: executes AT the coherence point (L3) ->
            // immediately visible to consumer sc0/sc1 loads on other XCDs.
            (void)__hip_atomic_exchange(dst, __float_as_uint(h),
                                        __ATOMIC_RELAXED,
                                        __HIP_MEMORY_SCOPE_AGENT);
        }
    }
}

// ---------------------------------------------------------------------------
// scores[t,b,s] = sum_k hsTf[t][k][b]*W_lin[s][k] + hsTb[t][k][b]*W_lin[s][256+k]
//                 + b_lin[s].  One block per t.
// ---------------------------------------------------------------------------
__global__ __launch_bounds__(256) void scores_kernel(
    const float* __restrict__ hsTf, const float* __restrict__ hsTb,
    const float* __restrict__ W_lin, const float* __restrict__ b_lin,
    float* __restrict__ scores)
{
    __shared__ float As[128 * 64];   // As[k][b]
    __shared__ float Ws[128 * 64];   // Ws[k][s]
    const int t   = blockIdx.x;
    const int tid = threadIdx.x;
    const int bl  = tid & 63;
    const int kc  = tid >> 6;        // 0..3
    const int tb  = tid & 15;
    const int ts  = tid >> 4;

    float acc[4][4] = {};

    for (int chunk = 0; chunk < 4; ++chunk) {
        const int koff = chunk * 128;
        const float* srcA = (koff < 256)
            ? (hsTf + (size_t)t * KB16 + (size_t)koff * 64)
            : (hsTb + (size_t)t * KB16 + (size_t)(koff - 256) * 64);
        const float4* sA4 = (const float4*)srcA;
        float4* As4 = (float4*)As;
        #pragma unroll
        for (int i = 0; i < 8; ++i) As4[tid + i * 256] = sA4[tid + i * 256];
        const float4* wl4 = (const float4*)(W_lin + koff);  // row pitch 128 f4
        #pragma unroll
        for (int it = 0; it < 8; ++it) {
            const int k4 = it * 4 + kc;
            float4 wv = wl4[bl * 128 + k4];
            const int k = k4 * 4;
            Ws[(k + 0) * 64 + bl] = wv.x; Ws[(k + 1) * 64 + bl] = wv.y;
            Ws[(k + 2) * 64 + bl] = wv.z; Ws[(k + 3) * 64 + bl] = wv.w;
        }
        __syncthreads();
        #pragma unroll 4
        for (int k = 0; k < 128; ++k) {
            const float4 av = *(const float4*)&As[k * 64 + tb * 4];
            const float4 bv = *(const float4*)&Ws[k * 64 + ts * 4];
            acc[0][0] += av.x * bv.x; acc[0][1] += av.x * bv.y; acc[0][2] += av.x * bv.z; acc[0][3] += av.x * bv.w;
            acc[1][0] += av.y * bv.x; acc[1][1] += av.y * bv.y; acc[1][2] += av.y * bv.z; acc[1][3] += av.y * bv.w;
            acc[2][0] += av.z * bv.x; acc[2][1] += av.z * bv.y; acc[2][2] += av.z * bv.z; acc[2][3] += av.z * bv.w;
            acc[3][0] += av.w * bv.x; acc[3][1] += av.w * bv.y; acc[3][2] += av.w * bv.z; acc[3][3] += av.w * bv.w;
        }
        __syncthreads();
    }

    #pragma unroll
    for (int i = 0; i < 4; ++i) {
        const int bb = tb * 4 + i;
        #pragma unroll
        for (int j = 0; j < 4; ++j) {
            const int ss = ts * 4 + j;
            scores[(size_t)t * (BB * SS) + bb * SS + ss] = acc[i][j] + b_lin[ss];
        }
    }
}

// ---------------------------------------------------------------------------
// Viterbi forward + backtrace. One block per batch b; 256 threads:
// thread (s = tid&63, q = tid>>6) scans prev-states p in [q*16,(q+1)*16).
// Ascending strict-'>' scan + ascending combine == numpy first-index argmax.
// ---------------------------------------------------------------------------
__global__ __launch_bounds__(256) void viterbi_kernel(
    const float* __restrict__ scores, const float* __restrict__ pairwise,
    const float* __restrict__ start, const float* __restrict__ stop,
    float* __restrict__ out)
{
    __shared__ float delta[2][64];
    __shared__ float part[4][64];
    __shared__ int   pidx[4][64];
    __shared__ unsigned char bps[511 * 64];
    __shared__ float fin[64];

    const int b   = blockIdx.x;
    const int tid = threadIdx.x;
    const int s   = tid & 63;
    const int q   = tid >> 6;

    float pw[16];
    #pragma unroll
    for (int i = 0; i < 16; ++i)
        pw[i] = pairwise[(q * 16 + i) * 64 + s];

    if (q == 0) delta[0][s] = start[s] + scores[b * SS + s];
    __syncthreads();

    int cur = 0;
    for (int t = 1; t < TT; ++t) {
        float sc = 0.0f;
        if (q == 0) sc = scores[(size_t)t * (BB * SS) + b * SS + s];
        float best = -1e30f;
        int bp = q * 16;
        #pragma unroll
        for (int i = 0; i < 16; ++i) {
            const float v = delta[cur][q * 16 + i] + pw[i];   // broadcast read
            if (v > best) { best = v; bp = q * 16 + i; }
        }
        part[q][s] = best;
        pidx[q][s] = bp;
        __syncthreads();
        if (q == 0) {
            float m = part[0][s];
            int arg = pidx[0][s];
            #pragma unroll
            for (int qq = 1; qq < 4; ++qq) {
                const float v = part[qq][s];
                if (v > m) { m = v; arg = pidx[qq][s]; }
            }
            delta[cur ^ 1][s] = m + sc;
            bps[(t - 1) * 64 + s] = (unsigned char)arg;
        }
        cur ^= 1;
        __syncthreads();
    }

    if (q == 0) fin[s] = delta[cur][s] + stop[s];
    __syncthreads();

    if (tid == 0) {
        float m = fin[0];
        int arg = 0;
        for (int p = 1; p < 64; ++p)
            if (fin[p] > m) { m = fin[p]; arg = p; }
        out[b] = m;
        int st = arg;
        out[64 + 511 * 64 + b] = (float)st;
        for (int k = 510; k >= 0; --k) {
            st = bps[k * 64 + st];
            out[64 + k * 64 + b] = (float)st;
        }
    }
}

// ---------------------------------------------------------------------------
extern "C" void kernel_launch(void* const* d_in, const int* in_sizes, int n_in,
                              void* d_out, int out_size, void* d_ws, size_t ws_size,
                              hipStream_t stream)
{
    const int*   obs      = (const int*)d_in[0];
    const float* h0       = (const float*)d_in[1];
    const float* c0       = (const float*)d_in[2];
    const float* embed    = (const float*)d_in[3];
    const float* Wih_f    = (const float*)d_in[4];
    const float* Whh_f    = (const float*)d_in[5];
    const float* bih_f    = (const float*)d_in[6];
    const float* bhh_f    = (const float*)d_in[7];
    const float* Wih_b    = (const float*)d_in[8];
    const float* Whh_b    = (const float*)d_in[9];
    const float* bih_b    = (const float*)d_in[10];
    const float* bhh_b    = (const float*)d_in[11];
    const float* W_lin    = (const float*)d_in[12];
    const float* b_lin    = (const float*)d_in[13];
    const float* pairwise = (const float*)d_in[14];
    const float* start    = (const float*)d_in[15];
    const float* stop     = (const float*)d_in[16];
    (void)in_sizes; (void)n_in; (void)out_size; (void)ws_size;

    // ws layout (floats): embT | hsTf | hsTb | scores   (~104 MB)
    float* ws     = (float*)d_ws;
    float* embT   = ws;
    float* hsTf   = embT + (size_t)TT * KB16;
    float* hsTb   = hsTf + (size_t)TT * KB16;
    float* scores = hsTb + (size_t)TT * KB16;

    // sentinel-init hsTf+hsTb (contiguous, 64 MB): 0xFF bytes = float NaN
    hipMemsetAsync(hsTf, 0xFF, (size_t)2 * TT * KB16 * sizeof(float), stream);
    embT_prep<<<512, 256, 0, stream>>>(obs, embed, embT);
    lstm_persist<<<256, 512, 0, stream>>>(
        embT, Wih_f, Whh_f, bih_f, bhh_f, Wih_b, Whh_b, bih_b, bhh_b,
        h0, c0, hsTf, hsTb);
    scores_kernel<<<512, 256, 0, stream>>>(hsTf, hsTb, W_lin, b_lin, scores);
    viterbi_kernel<<<64, 256, 0, stream>>>(scores, pairwise, start, stop, (float*)d_out);
}